// Round 12
// baseline (270.922 us; speedup 1.0000x reference)
//
#include <hip/hip_runtime.h>

// ---------------------------------------------------------------------------
// Attention_28561532519042: GCN-projection + BN + ReLU + causal time-attention
// B2=400 (=16 batch x 25 joints), T=120, C=128, QKV_C=1536, HEADS=8, DH=64
// Pipeline:
//   K0  prep          : (fused) fold BN into Wcat[1536x512] bf16, Wout bf16,
//                       bias  +  Zt[48000x512] bf16, rows n=(b*25+v)*120+t
//   K2  gemm_qkv      : QKV = relu(Wcat.Zt + bias); BK=64 double-buffered
//                       8-phase loop (32 MFMA/phase/wave), G4 XOR-swizzled LDS;
//                       Q/K via LDS-transpose epilogue, V^T direct   [r7 best]
//   K3  attn_k        : per (b2,h): split K/V waits, S=QK^T/8 causal ->
//                       softmax -> P bf16 LDS -> attn stores issued BEFORE PV
//                       (retire under MFMA) -> PV -> og bf16
//   K4  gemm_out_k    : out = o_ws . Wout^T + out_b, BK=64 dbuf 8-phase [r7]
// ---------------------------------------------------------------------------

typedef __bf16 bf16;
typedef __bf16 bf16x8 __attribute__((ext_vector_type(8)));
typedef __bf16 bf16x4 __attribute__((ext_vector_type(4)));
typedef float  f32x4  __attribute__((ext_vector_type(4)));
typedef __attribute__((address_space(1))) const void* gptr1;
typedef __attribute__((address_space(3))) void*       lptr3;

#define GLL16(g, l) __builtin_amdgcn_global_load_lds((gptr1)(g), (lptr3)(l), 16, 0, 0)
#define MFMA16(a, b, c) __builtin_amdgcn_mfma_f32_16x16x32_bf16(a, b, c, 0, 0, 0)

// ---------------- K0: fused weight-fold + Zt transform --------------------
// blocks [0,3334): build_weights body; blocks [3334,5254): transform body.
__global__ __launch_bounds__(256) void prep(
    const float* __restrict__ conv_w, const float* __restrict__ conv_b,
    const float* __restrict__ g1, const float* __restrict__ be1,
    const float* __restrict__ mu1, const float* __restrict__ va1,
    const float* __restrict__ down_w, const float* __restrict__ down_b,
    const float* __restrict__ g2, const float* __restrict__ be2,
    const float* __restrict__ mu2, const float* __restrict__ va2,
    const float* __restrict__ out_w,
    const float* __restrict__ x, const float* __restrict__ A,
    bf16* __restrict__ wcat, bf16* __restrict__ wout, float* __restrict__ bias,
    bf16* __restrict__ zt)
{
    __shared__ float xs[25][128];
    const int tid = threadIdx.x;
    if (blockIdx.x < 3334) {
        // ---- build_weights ----
        int idx = blockIdx.x * 256 + tid;
        if (idx < 1536 * 512) {
            int o = idx >> 9, k = idx & 511;
            float s, w;
            if (k < 384) {
                int h = k >> 7, c = k & 127;
                s = g1[o] * rsqrtf(va1[o] + 1e-5f);
                w = conv_w[(h * 1536 + o) * 128 + c];
            } else {
                s = g2[o] * rsqrtf(va2[o] + 1e-5f);
                w = down_w[o * 128 + (k - 384)];
            }
            wcat[idx] = (bf16)(w * s);
        }
        int i2 = idx - 1536 * 512;
        if (i2 >= 0 && i2 < 128 * 512) wout[i2] = (bf16)out_w[i2];
        int i3 = idx - (1536 * 512 + 128 * 512);
        if (i3 >= 0 && i3 < 1536) {
            int o = i3;
            float s1 = g1[o] * rsqrtf(va1[o] + 1e-5f);
            float s2 = g2[o] * rsqrtf(va2[o] + 1e-5f);
            float cb = conv_b[o] + conv_b[1536 + o] + conv_b[2 * 1536 + o];
            bias[o] = cb * s1 + be1[o] - mu1[o] * s1
                    + down_b[o] * s2 + be2[o] - mu2[o] * s2;
        }
        return;
    }
    // ---- transform: Zt rows n=(b*25+v)*120+t ----
    const int bt = blockIdx.x - 3334;
    const int b = bt / 120, t = bt - b * 120;
    for (int i = tid; i < 25 * 128; i += 256) {
        int u = i >> 7, c = i & 127;
        xs[u][c] = x[((size_t)(b * 25 + u) * 120 + t) * 128 + c];
    }
    __syncthreads();
    const int c = tid & 127, g = tid >> 7;   // g in {0,1}, wave-uniform
    float xr[25];
    #pragma unroll
    for (int u = 0; u < 25; u++) xr[u] = xs[u][c];
    for (int idx = g; idx < 75; idx += 2) {      // (h,v) combos
        int h = idx / 25, v = idx - h * 25;
        const float* Ap = A + (h * 25 + v) * 25;
        float acc = 0.f;
        #pragma unroll
        for (int u = 0; u < 25; u++) acc += Ap[u] * xr[u];
        zt[((size_t)(b * 25 + v) * 120 + t) * 512 + h * 128 + c] = (bf16)acc;
    }
    for (int v = g; v < 25; v += 2)
        zt[((size_t)(b * 25 + v) * 120 + t) * 512 + 384 + c] = (bf16)xs[v][c];
}

// ---------------- K2: QKV GEMM 1536 x 48000 x 512 -------------------------
// BK=64 double-buffer (2 x 32KB), 8 phases, 32 MFMA/phase/wave.  [r7 verbatim]
__global__ __launch_bounds__(256) void gemm_qkv(
    const bf16* __restrict__ wcat, const bf16* __restrict__ zt,
    const float* __restrict__ bias,
    bf16* __restrict__ qg, bf16* __restrict__ kg, bf16* __restrict__ vtg)
{
    __shared__ __align__(16) char smem[65536];   // 2 x (A 16KB + B 16KB); Lt 32KB
    const int tid = threadIdx.x, lane = tid & 63, wv = tid >> 6;
    const int wrow = wv >> 1, wcol = wv & 1;
    // bijective XCD swizzle: same-nt blocks land on one XCD (m204)
    const int NB = 4500, q8 = NB >> 3, r8 = NB & 7;   // 562, 4
    const int xcd = blockIdx.x & 7, sidx = blockIdx.x >> 3;
    const int vid = (xcd < r8 ? xcd * (q8 + 1) : r8 * (q8 + 1) + (xcd - r8) * q8) + sidx;
    const int mt = vid % 12, nt = vid / 12;
    const int colb = lane & 15, rg = lane >> 4;

    f32x4 acc[4][4];
    #pragma unroll
    for (int i = 0; i < 4; i++)
        #pragma unroll
        for (int j = 0; j < 4; j++) acc[i][j] = (f32x4){0.f, 0.f, 0.f, 0.f};

    const char* gA = (const char*)wcat + (size_t)mt * 128 * 1024; // 1024B rows
    const char* gB = (const char*)zt + (size_t)nt * 128 * 1024;

    // fragment read offsets: row = (wrow|wcol)*64 + m*16 + colb, 128B rows
    int aoff[4][2], boff[4][2];
    #pragma unroll
    for (int m = 0; m < 4; m++)
        #pragma unroll
        for (int kk = 0; kk < 2; kk++) {
            int swz = (rg * 16 + kk * 64) ^ ((colb & 7) << 4);
            aoff[m][kk] = (wrow * 64 + m * 16 + colb) * 128 + swz;
            boff[m][kk] = (wcol * 64 + m * 16 + colb) * 128 + swz;
        }

    // stage one BK=64 tile: 1024 16B-chunks each for A and B (4+4 GLL/thread)
    #define STG(kt, bsel) do {                                                  \
        char* As_ = smem + (bsel) * 32768; char* Bs_ = As_ + 16384;             \
        _Pragma("unroll")                                                       \
        for (int j = 0; j < 4; j++) {                                           \
            int c = j * 256 + tid;                                              \
            int r = c >> 3, sl = (c & 7) ^ (r & 7);                             \
            GLL16(gA + (size_t)r * 1024 + (kt) * 128 + sl * 16, As_ + c * 16);  \
            GLL16(gB + (size_t)r * 1024 + (kt) * 128 + sl * 16, Bs_ + c * 16);  \
        } } while (0)

    STG(0, 0);
    asm volatile("s_waitcnt vmcnt(0)" ::: "memory");
    __builtin_amdgcn_s_barrier();
    for (int p = 0; p < 8; p++) {
        const char* As = smem + (p & 1) * 32768;
        const char* Bs = As + 16384;
        if (p < 7) STG(p + 1, (p + 1) & 1);          // fills the idle buffer
        bf16x8 af[4][2], bfr[4][2];
        #pragma unroll
        for (int m = 0; m < 4; m++)
            #pragma unroll
            for (int kk = 0; kk < 2; kk++) {
                af[m][kk]  = *(const bf16x8*)(As + aoff[m][kk]);
                bfr[m][kk] = *(const bf16x8*)(Bs + boff[m][kk]);
            }
        __builtin_amdgcn_s_setprio(1);
        #pragma unroll
        for (int m = 0; m < 4; m++)
            #pragma unroll
            for (int n = 0; n < 4; n++)
                #pragma unroll
                for (int kk = 0; kk < 2; kk++)
                    acc[m][n] = MFMA16(af[m][kk], bfr[n][kk], acc[m][n]);
        __builtin_amdgcn_s_setprio(0);
        asm volatile("s_waitcnt vmcnt(0)" ::: "memory"); // next tile landed
        __builtin_amdgcn_s_barrier();
    }
    __builtin_amdgcn_sched_barrier(0);

    const int mtb = mt * 128, ntb = nt * 128;
    const int which = mtb >> 9;                  // 0=Q, 1=K, 2=V (block-uniform)

    if (which < 2) {
        // ---- LDS-transpose epilogue: Lt[n'][o'] bf16, XOR-swizzled rows ----
        bf16* Lt = (bf16*)smem;                  // [128][128] -> 256B rows
        const float qs = (which == 0) ? 0.125f : 1.0f;
        #pragma unroll
        for (int m = 0; m < 4; m++) {
            int o0 = wrow * 64 + m * 16 + rg * 4;
            float b0 = bias[mtb + o0 + 0], b1 = bias[mtb + o0 + 1];
            float b2 = bias[mtb + o0 + 2], b3 = bias[mtb + o0 + 3];
            #pragma unroll
            for (int nn = 0; nn < 4; nn++) {
                int n_ = wcol * 64 + nn * 16 + colb;
                bf16x4 pk;
                pk[0] = (bf16)(fmaxf(acc[m][nn][0] + b0, 0.f) * qs);
                pk[1] = (bf16)(fmaxf(acc[m][nn][1] + b1, 0.f) * qs);
                pk[2] = (bf16)(fmaxf(acc[m][nn][2] + b2, 0.f) * qs);
                pk[3] = (bf16)(fmaxf(acc[m][nn][3] + b3, 0.f) * qs);
                *(bf16x4*)((char*)Lt + n_ * 256 + ((o0 * 2) ^ ((n_ & 7) << 4))) = pk;
            }
        }
        __syncthreads();
        bf16* dst = (which == 0) ? qg : kg;
        #pragma unroll
        for (int i = 0; i < 8; i++) {
            int ch = i * 256 + tid;
            int n_ = ch >> 4, c16 = ch & 15;
            int ng = ntb + n_;
            int grp = ng / 120, t = ng - grp * 120;      // grp = b*25+v
            int o = mtb + c16 * 8;
            int hd = (o >> 6) & 7, dd0 = o & 63;
            bf16x8 vv = *(const bf16x8*)((const char*)Lt + n_ * 256 +
                                         ((c16 * 16) ^ ((n_ & 7) << 4)));
            *(bf16x8*)(dst + ((size_t)(grp * 8 + hd) * 120 + t) * 64 + dd0) = vv;
        }
    } else {
        // ---- V^T direct: t contiguous across colb -> 32B lane-runs ---------
        #pragma unroll
        for (int m = 0; m < 4; m++) {
            #pragma unroll
            for (int reg = 0; reg < 4; reg++) {
                int o = mtb + wrow * 64 + m * 16 + rg * 4 + reg;
                float bo = bias[o];
                int hd = (o >> 6) & 7, dd = o & 63;
                #pragma unroll
                for (int nn = 0; nn < 4; nn++) {
                    int n = ntb + wcol * 64 + nn * 16 + colb;
                    int grp = n / 120, t = n - grp * 120;
                    float val = fmaxf(acc[m][nn][reg] + bo, 0.f);
                    vtg[((size_t)(grp * 8 + hd) * 64 + dd) * 128 + t] = (bf16)val;
                }
            }
        }
    }
    #undef STG
}

// ---------------- K3: causal attention per (b2, head) ---------------------
// LDS 48KB: Vt[16KB] | Ks[16KB] ; Ps[32KB] aliases Ks after QK^T.
// Split waits: vmcnt(4) -> K(+Q) landed, V's 4 GLLs ride through QK^T.
// attn stores issued BEFORE PV so they retire under the MFMA cluster.
__global__ __launch_bounds__(256) void attn_k(
    const bf16* __restrict__ qg, const bf16* __restrict__ kg,
    const bf16* __restrict__ vtg, float* __restrict__ attn_out,
    bf16* __restrict__ og)
{
    __shared__ __align__(16) char sm[49152];
    char* Vt = sm;                // [d][t] 256B rows, XOR-swizzled  (16KB)
    char* Ks = sm + 16384;        // [t][d] 128B rows, XOR-swizzled  (16KB)
    char* Ps = sm + 16384;        // [tq][tk] 256B rows, XOR-swizzled (32KB)
    const int tid = threadIdx.x, lane = tid & 63, wv = tid >> 6;
    const int bh = blockIdx.x;
    const int colb = lane & 15, rg = lane >> 4;

    const char* ksrc = (const char*)kg + (size_t)bh * 15360;
    const char* vsrc = (const char*)vtg + (size_t)bh * 16384;
    #pragma unroll
    for (int is = 0; is < 4; is++) {
        int cb = is * 256 + wv * 64;             // wave-uniform chunk base
        if (cb < 960) {
            int bb = (cb + lane) * 16;
            int row = bb >> 7;
            int gsrc = (bb & ~127) | ((bb & 127) ^ ((row & 7) << 4));
            GLL16(ksrc + gsrc, Ks + cb * 16);
        }
    }
    const char* qsrc = (const char*)qg + (size_t)bh * 15360;
    bf16x8 qf[2][2];
    #pragma unroll
    for (int kk = 0; kk < 2; kk++)
        #pragma unroll
        for (int m = 0; m < 2; m++) {
            int row = wv * 32 + m * 16 + colb;
            qf[kk][m] = *(const bf16x8*)(qsrc + (size_t)row * 128 + rg * 16 + kk * 64);
        }
    #pragma unroll
    for (int is = 0; is < 4; is++) {
        int cb = is * 256 + wv * 64;
        int bb = (cb + lane) * 16;
        int row = bb >> 8;
        int gsrc = (bb & ~255) | ((bb & 255) ^ ((row & 7) << 4));
        GLL16(vsrc + gsrc, Vt + cb * 16);
    }
    asm volatile("s_waitcnt vmcnt(4)" ::: "memory");   // K (+Q) done; 4 V in flight
    __builtin_amdgcn_s_barrier();
    if (tid < 64) {
        f32x4 z = {0.f, 0.f, 0.f, 0.f};
        int r = 120 + (tid >> 3), off = (tid & 7) * 16;
        *(f32x4*)(Ks + r * 128 + off) = z;
    }
    asm volatile("s_waitcnt lgkmcnt(0)" ::: "memory");
    __builtin_amdgcn_s_barrier();

    // S = Q.K^T (q pre-scaled by 1/8 in K2)
    f32x4 accs[2][8];
    #pragma unroll
    for (int m = 0; m < 2; m++)
        #pragma unroll
        for (int ct = 0; ct < 8; ct++) accs[m][ct] = (f32x4){0.f, 0.f, 0.f, 0.f};
    #pragma unroll
    for (int kk = 0; kk < 2; kk++) {
        #pragma unroll
        for (int ct = 0; ct < 8; ct++) {
            int rk = ct * 16 + colb;
            int byo = rk * 128 + ((rg * 16 + kk * 64) ^ ((rk & 7) << 4));
            bf16x8 bk = *(const bf16x8*)(Ks + byo);
            accs[0][ct] = MFMA16(qf[kk][0], bk, accs[0][ct]);
            accs[1][ct] = MFMA16(qf[kk][1], bk, accs[1][ct]);
        }
    }
    asm volatile("s_waitcnt vmcnt(0)" ::: "memory");   // V landed; Ks dead
    __builtin_amdgcn_s_barrier();
    if (tid >= 64 && tid < 128) {
        int d = tid - 64;
        f32x4 z = {0.f, 0.f, 0.f, 0.f};
        *(f32x4*)(Vt + d * 256 + (240 ^ ((d & 7) << 4))) = z;
    }

    // causal softmax; P (=p*inv) bf16 to LDS only
    const int rqb = wv * 32;
    #pragma unroll
    for (int m = 0; m < 2; m++) {
        #pragma unroll
        for (int reg = 0; reg < 4; reg++) {
            int t_q = rqb + m * 16 + rg * 4 + reg;
            float s[8], mx = -1e30f;
            #pragma unroll
            for (int ct = 0; ct < 8; ct++) {
                int col = ct * 16 + colb;
                bool valid = (col <= t_q) && (col < 120);
                s[ct] = valid ? accs[m][ct][reg] : -1e30f;
                mx = fmaxf(mx, s[ct]);
            }
            #pragma unroll
            for (int d = 1; d < 16; d <<= 1) mx = fmaxf(mx, __shfl_xor(mx, d, 64));
            float p[8], sum = 0.f;
            #pragma unroll
            for (int ct = 0; ct < 8; ct++) {
                p[ct] = (s[ct] > -1e29f) ? __expf(s[ct] - mx) : 0.f;
                sum += p[ct];
            }
            #pragma unroll
            for (int d = 1; d < 16; d <<= 1) sum += __shfl_xor(sum, d, 64);
            float inv = 1.f / sum;
            #pragma unroll
            for (int ct = 0; ct < 8; ct++) {
                int col = ct * 16 + colb;
                int byo = t_q * 256 + ((col * 2) ^ ((t_q & 7) << 4));
                *(bf16*)(Ps + byo) = (bf16)(p[ct] * inv);
            }
        }
    }
    asm volatile("s_waitcnt lgkmcnt(0)" ::: "memory");
    __builtin_amdgcn_s_barrier();

    // coalesced attn write FIRST: 120x120 fp32 from Ps (3600 x 16B chunks,
    // lane-contiguous). Fire-and-forget stores retire under the PV MFMAs.
    {
        float* attn_base = attn_out + (size_t)bh * 14400;
        #pragma unroll
        for (int i = 0; i < 15; i++) {
            int chunk = i * 256 + tid;
            if (chunk < 3600) {
                int r = chunk / 30, c4 = chunk - r * 30;
                int byo = r * 256 + ((c4 * 8) ^ ((r & 7) << 4));
                bf16x4 pv4 = *(const bf16x4*)(Ps + byo);
                f32x4 o4 = { (float)pv4[0], (float)pv4[1],
                             (float)pv4[2], (float)pv4[3] };
                *(f32x4*)(attn_base + chunk * 4) = o4;
            }
        }
    }

    // O = P.V ; causal skip: P rows of wave wv have zero cols >= 32*(wv+1)
    f32x4 acco[2][4];
    #pragma unroll
    for (int m = 0; m < 2; m++)
        #pragma unroll
        for (int dt = 0; dt < 4; dt++) acco[m][dt] = (f32x4){0.f, 0.f, 0.f, 0.f};
    for (int kk = 0; kk <= wv; kk++) {
        bf16x8 ap[2];
        #pragma unroll
        for (int m = 0; m < 2; m++) {
            int row = rqb + m * 16 + colb;
            int byo = row * 256 + ((rg * 16 + kk * 64) ^ ((row & 7) << 4));
            ap[m] = *(const bf16x8*)(Ps + byo);
        }
        #pragma unroll
        for (int dt = 0; dt < 4; dt++) {
            int rd = dt * 16 + colb;
            int byo = rd * 256 + ((rg * 16 + kk * 64) ^ ((rd & 7) << 4));
            bf16x8 bv = *(const bf16x8*)(Vt + byo);
            acco[0][dt] = MFMA16(ap[0], bv, acco[0][dt]);
            acco[1][dt] = MFMA16(ap[1], bv, acco[1][dt]);
        }
    }

    const int b2 = bh >> 3, h = bh & 7;
    #pragma unroll
    for (int m = 0; m < 2; m++)
        #pragma unroll
        for (int dt = 0; dt < 4; dt++)
            #pragma unroll
            for (int reg = 0; reg < 4; reg++) {
                int t = rqb + m * 16 + rg * 4 + reg;
                if (t < 120) {
                    int dfull = h * 64 + dt * 16 + colb;
                    og[((size_t)b2 * 120 + t) * 512 + dfull] = (bf16)acco[m][dt][reg];
                }
            }
}

// ---------------- K4: out = o . Wout^T + out_b  (48000 x 128 x 512) -------
// Same BK=64 double-buffered 8-phase structure as K2. [r7 verbatim]
__global__ __launch_bounds__(256) void gemm_out_k(
    const bf16* __restrict__ og, const bf16* __restrict__ wout,
    const float* __restrict__ outb, float* __restrict__ out)
{
    __shared__ __align__(16) char smem[65536];
    const int tid = threadIdx.x, lane = tid & 63, wv = tid >> 6;
    const int wrow = wv >> 1, wcol = wv & 1;
    const int nt = blockIdx.x;
    const int colb = lane & 15, rg = lane >> 4;

    f32x4 acc[4][4];
    #pragma unroll
    for (int i = 0; i < 4; i++)
        #pragma unroll
        for (int j = 0; j < 4; j++) acc[i][j] = (f32x4){0.f, 0.f, 0.f, 0.f};

    const char* gA = (const char*)og + (size_t)nt * 128 * 1024;
    const char* gB = (const char*)wout;

    int aoff[4][2], boff[4][2];
    #pragma unroll
    for (int m = 0; m < 4; m++)
        #pragma unroll
        for (int kk = 0; kk < 2; kk++) {
            int swz = (rg * 16 + kk * 64) ^ ((colb & 7) << 4);
            aoff[m][kk] = (wrow * 64 + m * 16 + colb) * 128 + swz;
            boff[m][kk] = (wcol * 64 + m * 16 + colb) * 128 + swz;
        }

    #define STG_O(kt, bsel) do {                                                \
        char* As_ = smem + (bsel) * 32768; char* Bs_ = As_ + 16384;             \
        _Pragma("unroll")                                                       \
        for (int j = 0; j < 4; j++) {                                           \
            int c = j * 256 + tid;                                              \
            int r = c >> 3, sl = (c & 7) ^ (r & 7);                             \
            GLL16(gA + (size_t)r * 1024 + (kt) * 128 + sl * 16, As_ + c * 16);  \
            GLL16(gB + (size_t)r * 1024 + (kt) * 128 + sl * 16, Bs_ + c * 16);  \
        } } while (0)

    STG_O(0, 0);
    asm volatile("s_waitcnt vmcnt(0)" ::: "memory");
    __builtin_amdgcn_s_barrier();
    for (int p = 0; p < 8; p++) {
        const char* As = smem + (p & 1) * 32768;
        const char* Bs = As + 16384;
        if (p < 7) STG_O(p + 1, (p + 1) & 1);
        bf16x8 af[4][2], bfr[4][2];
        #pragma unroll
        for (int m = 0; m < 4; m++)
            #pragma unroll
            for (int kk = 0; kk < 2; kk++) {
                af[m][kk]  = *(const bf16x8*)(As + aoff[m][kk]);
                bfr[m][kk] = *(const bf16x8*)(Bs + boff[m][kk]);
            }
        __builtin_amdgcn_s_setprio(1);
        #pragma unroll
        for (int m = 0; m < 4; m++)
            #pragma unroll
            for (int n = 0; n < 4; n++)
                #pragma unroll
                for (int kk = 0; kk < 2; kk++)
                    acc[m][n] = MFMA16(af[m][kk], bfr[n][kk], acc[m][n]);
        __builtin_amdgcn_s_setprio(0);
        asm volatile("s_waitcnt vmcnt(0)" ::: "memory");
        __builtin_amdgcn_s_barrier();
    }
    __builtin_amdgcn_sched_barrier(0);

    const int rbase = nt * 128 + wrow * 64;
    #pragma unroll
    for (int m = 0; m < 4; m++)
        #pragma unroll
        for (int reg = 0; reg < 4; reg++) {
            int r = rbase + m * 16 + rg * 4 + reg;
            #pragma unroll
            for (int nn = 0; nn < 4; nn++) {
                int c = wcol * 64 + nn * 16 + colb;
                out[(size_t)r * 128 + c] = acc[m][nn][reg] + outb[c];
            }
        }
    #undef STG_O
}

// ---------------- launch ---------------------------------------------------
extern "C" void kernel_launch(void* const* d_in, const int* in_sizes, int n_in,
                              void* d_out, int out_size, void* d_ws, size_t ws_size,
                              hipStream_t stream)
{
    (void)in_sizes; (void)n_in; (void)out_size; (void)ws_size;
    const float* x      = (const float*)d_in[0];
    const float* A      = (const float*)d_in[1];
    const float* conv_w = (const float*)d_in[2];
    const float* conv_b = (const float*)d_in[3];
    const float* bn_g   = (const float*)d_in[4];
    const float* bn_b   = (const float*)d_in[5];
    const float* bn_m   = (const float*)d_in[6];
    const float* bn_v   = (const float*)d_in[7];
    const float* dw     = (const float*)d_in[8];
    const float* db     = (const float*)d_in[9];
    const float* dg     = (const float*)d_in[10];
    const float* dbb    = (const float*)d_in[11];
    const float* dm     = (const float*)d_in[12];
    const float* dvv    = (const float*)d_in[13];
    const float* out_w  = (const float*)d_in[14];
    const float* out_b  = (const float*)d_in[15];

    char* ws = (char*)d_ws;
    const size_t OFF_WCAT = 0;                       // 1536*512*2   = 1,572,864
    const size_t OFF_WOUT = 1572864;                 // 128*512*2    =   131,072
    const size_t OFF_BIAS = 1703936;                 // 1536*4       =     6,144
    const size_t OFF_ZT   = 1710080;                 // 48000*512*2  = 49,152,000
    const size_t OFF_Q    = 50862080;                // 3200*120*64*2= 49,152,000
    const size_t OFF_K    = 100014080;               // 49,152,000
    const size_t OFF_VT   = 149166080;               // 3200*64*128*2= 52,428,800
    const size_t OFF_O    = OFF_ZT;                  // reuse Zt region after K2

    bf16*  wcat = (bf16*)(ws + OFF_WCAT);
    bf16*  wout = (bf16*)(ws + OFF_WOUT);
    float* bias = (float*)(ws + OFF_BIAS);
    bf16*  zt   = (bf16*)(ws + OFF_ZT);
    bf16*  qg   = (bf16*)(ws + OFF_Q);
    bf16*  kg   = (bf16*)(ws + OFF_K);
    bf16*  vtg  = (bf16*)(ws + OFF_VT);
    bf16*  og   = (bf16*)(ws + OFF_O);
    float* outp = (float*)d_out;
    float* attn = outp + 6144000;                    // out (400,120,128) first

    prep<<<5254, 256, 0, stream>>>(conv_w, conv_b, bn_g, bn_b, bn_m, bn_v,
                                   dw, db, dg, dbb, dm, dvv, out_w,
                                   x, A, wcat, wout, bias, zt);
    gemm_qkv<<<4500, 256, 0, stream>>>(wcat, zt, bias, qg, kg, vtg);
    attn_k<<<3200, 256, 0, stream>>>(qg, kg, vtg, attn, og);
    gemm_out_k<<<375, 256, 0, stream>>>(og, wout, out_b, outp);
}

// Round 13
// 262.483 us; speedup vs baseline: 1.0321x; 1.0321x over previous
//
#include <hip/hip_runtime.h>

// ---------------------------------------------------------------------------
// Attention_28561532519042: GCN-projection + BN + ReLU + causal time-attention
// B2=400 (=16 batch x 25 joints), T=120, C=128, QKV_C=1536, HEADS=8, DH=64
// FINAL (r7/r10 best-known, twice measured 262.9/263.2 us):
//   K1b build_weights : fold BN scales into Wcat[1536x512] bf16, Wout bf16, bias
//   K1  transform     : Zt[48000x512] bf16, rows n=(b*25+v)*120+t
//   K2  gemm_qkv      : QKV = relu(Wcat.Zt + bias); BK=64 double-buffered
//                       8-phase loop (32 MFMA/phase/wave), G4 XOR-swizzled LDS;
//                       Q/K via LDS-transpose epilogue, V^T direct
//   K3  attn_k        : per (b2,h): split K/V waits, S=QK^T/8 causal ->
//                       softmax -> P bf16 LDS -> PV -> coalesced attn pass
//   K4  gemm_out_k    : out = o_ws . Wout^T + out_b, same BK=64 structure
// ---------------------------------------------------------------------------

typedef __bf16 bf16;
typedef __bf16 bf16x8 __attribute__((ext_vector_type(8)));
typedef __bf16 bf16x4 __attribute__((ext_vector_type(4)));
typedef float  f32x4  __attribute__((ext_vector_type(4)));
typedef __attribute__((address_space(1))) const void* gptr1;
typedef __attribute__((address_space(3))) void*       lptr3;

#define GLL16(g, l) __builtin_amdgcn_global_load_lds((gptr1)(g), (lptr3)(l), 16, 0, 0)
#define MFMA16(a, b, c) __builtin_amdgcn_mfma_f32_16x16x32_bf16(a, b, c, 0, 0, 0)

// ---------------- K1b: fold BN into weights -------------------------------
__global__ __launch_bounds__(256) void build_weights(
    const float* __restrict__ conv_w, const float* __restrict__ conv_b,
    const float* __restrict__ g1, const float* __restrict__ be1,
    const float* __restrict__ mu1, const float* __restrict__ va1,
    const float* __restrict__ down_w, const float* __restrict__ down_b,
    const float* __restrict__ g2, const float* __restrict__ be2,
    const float* __restrict__ mu2, const float* __restrict__ va2,
    const float* __restrict__ out_w,
    bf16* __restrict__ wcat, bf16* __restrict__ wout, float* __restrict__ bias)
{
    int idx = blockIdx.x * 256 + threadIdx.x;
    if (idx < 1536 * 512) {
        int o = idx >> 9, k = idx & 511;
        float s, w;
        if (k < 384) {
            int h = k >> 7, c = k & 127;
            s = g1[o] * rsqrtf(va1[o] + 1e-5f);
            w = conv_w[(h * 1536 + o) * 128 + c];
        } else {
            s = g2[o] * rsqrtf(va2[o] + 1e-5f);
            w = down_w[o * 128 + (k - 384)];
        }
        wcat[idx] = (bf16)(w * s);
    }
    int i2 = idx - 1536 * 512;
    if (i2 >= 0 && i2 < 128 * 512) wout[i2] = (bf16)out_w[i2];
    int i3 = idx - (1536 * 512 + 128 * 512);
    if (i3 >= 0 && i3 < 1536) {
        int o = i3;
        float s1 = g1[o] * rsqrtf(va1[o] + 1e-5f);
        float s2 = g2[o] * rsqrtf(va2[o] + 1e-5f);
        float cb = conv_b[o] + conv_b[1536 + o] + conv_b[2 * 1536 + o];
        bias[o] = cb * s1 + be1[o] - mu1[o] * s1
                + down_b[o] * s2 + be2[o] - mu2[o] * s2;
    }
}

// ---------------- K1: build Zt[48000][512], n = (b*25+v)*120+t ------------
__global__ __launch_bounds__(256) void transform(
    const float* __restrict__ x, const float* __restrict__ A,
    bf16* __restrict__ zt)
{
    __shared__ float xs[25][128];
    const int tid = threadIdx.x;
    const int bt = blockIdx.x;
    const int b = bt / 120, t = bt - b * 120;
    for (int i = tid; i < 25 * 128; i += 256) {
        int u = i >> 7, c = i & 127;
        xs[u][c] = x[((size_t)(b * 25 + u) * 120 + t) * 128 + c];
    }
    __syncthreads();
    const int c = tid & 127, g = tid >> 7;   // g in {0,1}, wave-uniform
    float xr[25];
    #pragma unroll
    for (int u = 0; u < 25; u++) xr[u] = xs[u][c];
    for (int idx = g; idx < 75; idx += 2) {      // (h,v) combos
        int h = idx / 25, v = idx - h * 25;
        const float* Ap = A + (h * 25 + v) * 25;
        float acc = 0.f;
        #pragma unroll
        for (int u = 0; u < 25; u++) acc += Ap[u] * xr[u];
        zt[((size_t)(b * 25 + v) * 120 + t) * 512 + h * 128 + c] = (bf16)acc;
    }
    for (int v = g; v < 25; v += 2)
        zt[((size_t)(b * 25 + v) * 120 + t) * 512 + 384 + c] = (bf16)xs[v][c];
}

// ---------------- K2: QKV GEMM 1536 x 48000 x 512 -------------------------
// BK=64 double-buffer (2 x 32KB), 8 phases, 32 MFMA/phase/wave.
// LDS tile [128 rows][128B]; G4 swizzle byte ^= ((row&7)<<4); GLL source
// carries the inverse permutation (linear LDS dest, rule #21).
__global__ __launch_bounds__(256) void gemm_qkv(
    const bf16* __restrict__ wcat, const bf16* __restrict__ zt,
    const float* __restrict__ bias,
    bf16* __restrict__ qg, bf16* __restrict__ kg, bf16* __restrict__ vtg)
{
    __shared__ __align__(16) char smem[65536];   // 2 x (A 16KB + B 16KB); Lt 32KB
    const int tid = threadIdx.x, lane = tid & 63, wv = tid >> 6;
    const int wrow = wv >> 1, wcol = wv & 1;
    // bijective XCD swizzle: same-nt blocks land on one XCD (m204)
    const int NB = 4500, q8 = NB >> 3, r8 = NB & 7;   // 562, 4
    const int xcd = blockIdx.x & 7, sidx = blockIdx.x >> 3;
    const int vid = (xcd < r8 ? xcd * (q8 + 1) : r8 * (q8 + 1) + (xcd - r8) * q8) + sidx;
    const int mt = vid % 12, nt = vid / 12;
    const int colb = lane & 15, rg = lane >> 4;

    f32x4 acc[4][4];
    #pragma unroll
    for (int i = 0; i < 4; i++)
        #pragma unroll
        for (int j = 0; j < 4; j++) acc[i][j] = (f32x4){0.f, 0.f, 0.f, 0.f};

    const char* gA = (const char*)wcat + (size_t)mt * 128 * 1024; // 1024B rows
    const char* gB = (const char*)zt + (size_t)nt * 128 * 1024;

    // fragment read offsets: row = (wrow|wcol)*64 + m*16 + colb, 128B rows
    int aoff[4][2], boff[4][2];
    #pragma unroll
    for (int m = 0; m < 4; m++)
        #pragma unroll
        for (int kk = 0; kk < 2; kk++) {
            int swz = (rg * 16 + kk * 64) ^ ((colb & 7) << 4);
            aoff[m][kk] = (wrow * 64 + m * 16 + colb) * 128 + swz;
            boff[m][kk] = (wcol * 64 + m * 16 + colb) * 128 + swz;
        }

    // stage one BK=64 tile: 1024 16B-chunks each for A and B (4+4 GLL/thread)
    #define STG(kt, bsel) do {                                                  \
        char* As_ = smem + (bsel) * 32768; char* Bs_ = As_ + 16384;             \
        _Pragma("unroll")                                                       \
        for (int j = 0; j < 4; j++) {                                           \
            int c = j * 256 + tid;                                              \
            int r = c >> 3, sl = (c & 7) ^ (r & 7);                             \
            GLL16(gA + (size_t)r * 1024 + (kt) * 128 + sl * 16, As_ + c * 16);  \
            GLL16(gB + (size_t)r * 1024 + (kt) * 128 + sl * 16, Bs_ + c * 16);  \
        } } while (0)

    STG(0, 0);
    asm volatile("s_waitcnt vmcnt(0)" ::: "memory");
    __builtin_amdgcn_s_barrier();
    for (int p = 0; p < 8; p++) {
        const char* As = smem + (p & 1) * 32768;
        const char* Bs = As + 16384;
        if (p < 7) STG(p + 1, (p + 1) & 1);          // fills the idle buffer
        bf16x8 af[4][2], bfr[4][2];
        #pragma unroll
        for (int m = 0; m < 4; m++)
            #pragma unroll
            for (int kk = 0; kk < 2; kk++) {
                af[m][kk]  = *(const bf16x8*)(As + aoff[m][kk]);
                bfr[m][kk] = *(const bf16x8*)(Bs + boff[m][kk]);
            }
        __builtin_amdgcn_s_setprio(1);
        #pragma unroll
        for (int m = 0; m < 4; m++)
            #pragma unroll
            for (int n = 0; n < 4; n++)
                #pragma unroll
                for (int kk = 0; kk < 2; kk++)
                    acc[m][n] = MFMA16(af[m][kk], bfr[n][kk], acc[m][n]);
        __builtin_amdgcn_s_setprio(0);
        asm volatile("s_waitcnt vmcnt(0)" ::: "memory"); // next tile landed
        __builtin_amdgcn_s_barrier();
    }
    __builtin_amdgcn_sched_barrier(0);

    const int mtb = mt * 128, ntb = nt * 128;
    const int which = mtb >> 9;                  // 0=Q, 1=K, 2=V (block-uniform)

    if (which < 2) {
        // ---- LDS-transpose epilogue: Lt[n'][o'] bf16, XOR-swizzled rows ----
        bf16* Lt = (bf16*)smem;                  // [128][128] -> 256B rows
        const float qs = (which == 0) ? 0.125f : 1.0f;
        #pragma unroll
        for (int m = 0; m < 4; m++) {
            int o0 = wrow * 64 + m * 16 + rg * 4;
            float b0 = bias[mtb + o0 + 0], b1 = bias[mtb + o0 + 1];
            float b2 = bias[mtb + o0 + 2], b3 = bias[mtb + o0 + 3];
            #pragma unroll
            for (int nn = 0; nn < 4; nn++) {
                int n_ = wcol * 64 + nn * 16 + colb;
                bf16x4 pk;
                pk[0] = (bf16)(fmaxf(acc[m][nn][0] + b0, 0.f) * qs);
                pk[1] = (bf16)(fmaxf(acc[m][nn][1] + b1, 0.f) * qs);
                pk[2] = (bf16)(fmaxf(acc[m][nn][2] + b2, 0.f) * qs);
                pk[3] = (bf16)(fmaxf(acc[m][nn][3] + b3, 0.f) * qs);
                *(bf16x4*)((char*)Lt + n_ * 256 + ((o0 * 2) ^ ((n_ & 7) << 4))) = pk;
            }
        }
        __syncthreads();
        bf16* dst = (which == 0) ? qg : kg;
        #pragma unroll
        for (int i = 0; i < 8; i++) {
            int ch = i * 256 + tid;
            int n_ = ch >> 4, c16 = ch & 15;
            int ng = ntb + n_;
            int grp = ng / 120, t = ng - grp * 120;      // grp = b*25+v
            int o = mtb + c16 * 8;
            int hd = (o >> 6) & 7, dd0 = o & 63;
            bf16x8 vv = *(const bf16x8*)((const char*)Lt + n_ * 256 +
                                         ((c16 * 16) ^ ((n_ & 7) << 4)));
            *(bf16x8*)(dst + ((size_t)(grp * 8 + hd) * 120 + t) * 64 + dd0) = vv;
        }
    } else {
        // ---- V^T direct: t contiguous across colb -> 32B lane-runs ---------
        #pragma unroll
        for (int m = 0; m < 4; m++) {
            #pragma unroll
            for (int reg = 0; reg < 4; reg++) {
                int o = mtb + wrow * 64 + m * 16 + rg * 4 + reg;
                float bo = bias[o];
                int hd = (o >> 6) & 7, dd = o & 63;
                #pragma unroll
                for (int nn = 0; nn < 4; nn++) {
                    int n = ntb + wcol * 64 + nn * 16 + colb;
                    int grp = n / 120, t = n - grp * 120;
                    float val = fmaxf(acc[m][nn][reg] + bo, 0.f);
                    vtg[((size_t)(grp * 8 + hd) * 64 + dd) * 128 + t] = (bf16)val;
                }
            }
        }
    }
    #undef STG
}

// ---------------- K3: causal attention per (b2, head) ---------------------
// LDS 48KB: Vt[16KB] | Ks[16KB] ; Ps[32KB] aliases Ks after QK^T.
// Split waits: vmcnt(4) -> K(+Q) landed, V's 4 GLLs ride through QK^T.
__global__ __launch_bounds__(256) void attn_k(
    const bf16* __restrict__ qg, const bf16* __restrict__ kg,
    const bf16* __restrict__ vtg, float* __restrict__ attn_out,
    bf16* __restrict__ og)
{
    __shared__ __align__(16) char sm[49152];
    char* Vt = sm;                // [d][t] 256B rows, XOR-swizzled  (16KB)
    char* Ks = sm + 16384;        // [t][d] 128B rows, XOR-swizzled  (16KB)
    char* Ps = sm + 16384;        // [tq][tk] 256B rows, XOR-swizzled (32KB)
    const int tid = threadIdx.x, lane = tid & 63, wv = tid >> 6;
    const int bh = blockIdx.x;
    const int colb = lane & 15, rg = lane >> 4;

    const char* ksrc = (const char*)kg + (size_t)bh * 15360;
    const char* vsrc = (const char*)vtg + (size_t)bh * 16384;
    #pragma unroll
    for (int is = 0; is < 4; is++) {
        int cb = is * 256 + wv * 64;             // wave-uniform chunk base
        if (cb < 960) {
            int bb = (cb + lane) * 16;
            int row = bb >> 7;
            int gsrc = (bb & ~127) | ((bb & 127) ^ ((row & 7) << 4));
            GLL16(ksrc + gsrc, Ks + cb * 16);
        }
    }
    const char* qsrc = (const char*)qg + (size_t)bh * 15360;
    bf16x8 qf[2][2];
    #pragma unroll
    for (int kk = 0; kk < 2; kk++)
        #pragma unroll
        for (int m = 0; m < 2; m++) {
            int row = wv * 32 + m * 16 + colb;
            qf[kk][m] = *(const bf16x8*)(qsrc + (size_t)row * 128 + rg * 16 + kk * 64);
        }
    #pragma unroll
    for (int is = 0; is < 4; is++) {
        int cb = is * 256 + wv * 64;
        int bb = (cb + lane) * 16;
        int row = bb >> 8;
        int gsrc = (bb & ~255) | ((bb & 255) ^ ((row & 7) << 4));
        GLL16(vsrc + gsrc, Vt + cb * 16);
    }
    asm volatile("s_waitcnt vmcnt(4)" ::: "memory");   // K (+Q) done; 4 V in flight
    __builtin_amdgcn_s_barrier();
    if (tid < 64) {
        f32x4 z = {0.f, 0.f, 0.f, 0.f};
        int r = 120 + (tid >> 3), off = (tid & 7) * 16;
        *(f32x4*)(Ks + r * 128 + off) = z;
    }
    asm volatile("s_waitcnt lgkmcnt(0)" ::: "memory");
    __builtin_amdgcn_s_barrier();

    // S = Q.K^T (q pre-scaled by 1/8 in K2)
    f32x4 accs[2][8];
    #pragma unroll
    for (int m = 0; m < 2; m++)
        #pragma unroll
        for (int ct = 0; ct < 8; ct++) accs[m][ct] = (f32x4){0.f, 0.f, 0.f, 0.f};
    #pragma unroll
    for (int kk = 0; kk < 2; kk++) {
        #pragma unroll
        for (int ct = 0; ct < 8; ct++) {
            int rk = ct * 16 + colb;
            int byo = rk * 128 + ((rg * 16 + kk * 64) ^ ((rk & 7) << 4));
            bf16x8 bk = *(const bf16x8*)(Ks + byo);
            accs[0][ct] = MFMA16(qf[kk][0], bk, accs[0][ct]);
            accs[1][ct] = MFMA16(qf[kk][1], bk, accs[1][ct]);
        }
    }
    asm volatile("s_waitcnt vmcnt(0)" ::: "memory");   // V landed; Ks dead
    __builtin_amdgcn_s_barrier();
    if (tid >= 64 && tid < 128) {
        int d = tid - 64;
        f32x4 z = {0.f, 0.f, 0.f, 0.f};
        *(f32x4*)(Vt + d * 256 + (240 ^ ((d & 7) << 4))) = z;
    }

    // causal softmax; P (=p*inv) bf16 to LDS only
    const int rqb = wv * 32;
    #pragma unroll
    for (int m = 0; m < 2; m++) {
        #pragma unroll
        for (int reg = 0; reg < 4; reg++) {
            int t_q = rqb + m * 16 + rg * 4 + reg;
            float s[8], mx = -1e30f;
            #pragma unroll
            for (int ct = 0; ct < 8; ct++) {
                int col = ct * 16 + colb;
                bool valid = (col <= t_q) && (col < 120);
                s[ct] = valid ? accs[m][ct][reg] : -1e30f;
                mx = fmaxf(mx, s[ct]);
            }
            #pragma unroll
            for (int d = 1; d < 16; d <<= 1) mx = fmaxf(mx, __shfl_xor(mx, d, 64));
            float p[8], sum = 0.f;
            #pragma unroll
            for (int ct = 0; ct < 8; ct++) {
                p[ct] = (s[ct] > -1e29f) ? __expf(s[ct] - mx) : 0.f;
                sum += p[ct];
            }
            #pragma unroll
            for (int d = 1; d < 16; d <<= 1) sum += __shfl_xor(sum, d, 64);
            float inv = 1.f / sum;
            #pragma unroll
            for (int ct = 0; ct < 8; ct++) {
                int col = ct * 16 + colb;
                int byo = t_q * 256 + ((col * 2) ^ ((t_q & 7) << 4));
                *(bf16*)(Ps + byo) = (bf16)(p[ct] * inv);
            }
        }
    }
    asm volatile("s_waitcnt lgkmcnt(0)" ::: "memory");
    __builtin_amdgcn_s_barrier();

    // O = P.V ; causal skip: P rows of wave wv have zero cols >= 32*(wv+1)
    f32x4 acco[2][4];
    #pragma unroll
    for (int m = 0; m < 2; m++)
        #pragma unroll
        for (int dt = 0; dt < 4; dt++) acco[m][dt] = (f32x4){0.f, 0.f, 0.f, 0.f};
    for (int kk = 0; kk <= wv; kk++) {
        bf16x8 ap[2];
        #pragma unroll
        for (int m = 0; m < 2; m++) {
            int row = rqb + m * 16 + colb;
            int byo = row * 256 + ((rg * 16 + kk * 64) ^ ((row & 7) << 4));
            ap[m] = *(const bf16x8*)(Ps + byo);
        }
        #pragma unroll
        for (int dt = 0; dt < 4; dt++) {
            int rd = dt * 16 + colb;
            int byo = rd * 256 + ((rg * 16 + kk * 64) ^ ((rd & 7) << 4));
            bf16x8 bv = *(const bf16x8*)(Vt + byo);
            acco[0][dt] = MFMA16(ap[0], bv, acco[0][dt]);
            acco[1][dt] = MFMA16(ap[1], bv, acco[1][dt]);
        }
    }

    // coalesced attn write: 120x120 fp32 from Ps (3600 x 16B, lane-contiguous)
    {
        float* attn_base = attn_out + (size_t)bh * 14400;
        #pragma unroll
        for (int i = 0; i < 15; i++) {
            int chunk = i * 256 + tid;
            if (chunk < 3600) {
                int r = chunk / 30, c4 = chunk - r * 30;
                int byo = r * 256 + ((c4 * 8) ^ ((r & 7) << 4));
                bf16x4 pv4 = *(const bf16x4*)(Ps + byo);
                f32x4 o4 = { (float)pv4[0], (float)pv4[1],
                             (float)pv4[2], (float)pv4[3] };
                *(f32x4*)(attn_base + chunk * 4) = o4;
            }
        }
    }

    const int b2 = bh >> 3, h = bh & 7;
    #pragma unroll
    for (int m = 0; m < 2; m++)
        #pragma unroll
        for (int dt = 0; dt < 4; dt++)
            #pragma unroll
            for (int reg = 0; reg < 4; reg++) {
                int t = rqb + m * 16 + rg * 4 + reg;
                if (t < 120) {
                    int dfull = h * 64 + dt * 16 + colb;
                    og[((size_t)b2 * 120 + t) * 512 + dfull] = (bf16)acco[m][dt][reg];
                }
            }
}

// ---------------- K4: out = o . Wout^T + out_b  (48000 x 128 x 512) -------
// Same BK=64 double-buffered 8-phase structure as K2.
__global__ __launch_bounds__(256) void gemm_out_k(
    const bf16* __restrict__ og, const bf16* __restrict__ wout,
    const float* __restrict__ outb, float* __restrict__ out)
{
    __shared__ __align__(16) char smem[65536];
    const int tid = threadIdx.x, lane = tid & 63, wv = tid >> 6;
    const int wrow = wv >> 1, wcol = wv & 1;
    const int nt = blockIdx.x;
    const int colb = lane & 15, rg = lane >> 4;

    f32x4 acc[4][4];
    #pragma unroll
    for (int i = 0; i < 4; i++)
        #pragma unroll
        for (int j = 0; j < 4; j++) acc[i][j] = (f32x4){0.f, 0.f, 0.f, 0.f};

    const char* gA = (const char*)og + (size_t)nt * 128 * 1024;
    const char* gB = (const char*)wout;

    int aoff[4][2], boff[4][2];
    #pragma unroll
    for (int m = 0; m < 4; m++)
        #pragma unroll
        for (int kk = 0; kk < 2; kk++) {
            int swz = (rg * 16 + kk * 64) ^ ((colb & 7) << 4);
            aoff[m][kk] = (wrow * 64 + m * 16 + colb) * 128 + swz;
            boff[m][kk] = (wcol * 64 + m * 16 + colb) * 128 + swz;
        }

    #define STG_O(kt, bsel) do {                                                \
        char* As_ = smem + (bsel) * 32768; char* Bs_ = As_ + 16384;             \
        _Pragma("unroll")                                                       \
        for (int j = 0; j < 4; j++) {                                           \
            int c = j * 256 + tid;                                              \
            int r = c >> 3, sl = (c & 7) ^ (r & 7);                             \
            GLL16(gA + (size_t)r * 1024 + (kt) * 128 + sl * 16, As_ + c * 16);  \
            GLL16(gB + (size_t)r * 1024 + (kt) * 128 + sl * 16, Bs_ + c * 16);  \
        } } while (0)

    STG_O(0, 0);
    asm volatile("s_waitcnt vmcnt(0)" ::: "memory");
    __builtin_amdgcn_s_barrier();
    for (int p = 0; p < 8; p++) {
        const char* As = smem + (p & 1) * 32768;
        const char* Bs = As + 16384;
        if (p < 7) STG_O(p + 1, (p + 1) & 1);
        bf16x8 af[4][2], bfr[4][2];
        #pragma unroll
        for (int m = 0; m < 4; m++)
            #pragma unroll
            for (int kk = 0; kk < 2; kk++) {
                af[m][kk]  = *(const bf16x8*)(As + aoff[m][kk]);
                bfr[m][kk] = *(const bf16x8*)(Bs + boff[m][kk]);
            }
        __builtin_amdgcn_s_setprio(1);
        #pragma unroll
        for (int m = 0; m < 4; m++)
            #pragma unroll
            for (int n = 0; n < 4; n++)
                #pragma unroll
                for (int kk = 0; kk < 2; kk++)
                    acc[m][n] = MFMA16(af[m][kk], bfr[n][kk], acc[m][n]);
        __builtin_amdgcn_s_setprio(0);
        asm volatile("s_waitcnt vmcnt(0)" ::: "memory");
        __builtin_amdgcn_s_barrier();
    }
    __builtin_amdgcn_sched_barrier(0);

    const int rbase = nt * 128 + wrow * 64;
    #pragma unroll
    for (int m = 0; m < 4; m++)
        #pragma unroll
        for (int reg = 0; reg < 4; reg++) {
            int r = rbase + m * 16 + rg * 4 + reg;
            #pragma unroll
            for (int nn = 0; nn < 4; nn++) {
                int c = wcol * 64 + nn * 16 + colb;
                out[(size_t)r * 128 + c] = acc[m][nn][reg] + outb[c];
            }
        }
    #undef STG_O
}

// ---------------- launch ---------------------------------------------------
extern "C" void kernel_launch(void* const* d_in, const int* in_sizes, int n_in,
                              void* d_out, int out_size, void* d_ws, size_t ws_size,
                              hipStream_t stream)
{
    (void)in_sizes; (void)n_in; (void)out_size; (void)ws_size;
    const float* x      = (const float*)d_in[0];
    const float* A      = (const float*)d_in[1];
    const float* conv_w = (const float*)d_in[2];
    const float* conv_b = (const float*)d_in[3];
    const float* bn_g   = (const float*)d_in[4];
    const float* bn_b   = (const float*)d_in[5];
    const float* bn_m   = (const float*)d_in[6];
    const float* bn_v   = (const float*)d_in[7];
    const float* dw     = (const float*)d_in[8];
    const float* db     = (const float*)d_in[9];
    const float* dg     = (const float*)d_in[10];
    const float* dbb    = (const float*)d_in[11];
    const float* dm     = (const float*)d_in[12];
    const float* dvv    = (const float*)d_in[13];
    const float* out_w  = (const float*)d_in[14];
    const float* out_b  = (const float*)d_in[15];

    char* ws = (char*)d_ws;
    const size_t OFF_WCAT = 0;                       // 1536*512*2   = 1,572,864
    const size_t OFF_WOUT = 1572864;                 // 128*512*2    =   131,072
    const size_t OFF_BIAS = 1703936;                 // 1536*4       =     6,144
    const size_t OFF_ZT   = 1710080;                 // 48000*512*2  = 49,152,000
    const size_t OFF_Q    = 50862080;                // 3200*120*64*2= 49,152,000
    const size_t OFF_K    = 100014080;               // 49,152,000
    const size_t OFF_VT   = 149166080;               // 3200*64*128*2= 52,428,800
    const size_t OFF_O    = OFF_ZT;                  // reuse Zt region after K2

    bf16*  wcat = (bf16*)(ws + OFF_WCAT);
    bf16*  wout = (bf16*)(ws + OFF_WOUT);
    float* bias = (float*)(ws + OFF_BIAS);
    bf16*  zt   = (bf16*)(ws + OFF_ZT);
    bf16*  qg   = (bf16*)(ws + OFF_Q);
    bf16*  kg   = (bf16*)(ws + OFF_K);
    bf16*  vtg  = (bf16*)(ws + OFF_VT);
    bf16*  og   = (bf16*)(ws + OFF_O);
    float* outp = (float*)d_out;
    float* attn = outp + 6144000;                    // out (400,120,128) first

    build_weights<<<3334, 256, 0, stream>>>(conv_w, conv_b, bn_g, bn_b, bn_m, bn_v,
                                            dw, db, dg, dbb, dm, dvv, out_w,
                                            wcat, wout, bias);
    transform<<<1920, 256, 0, stream>>>(x, A, zt);
    gemm_qkv<<<4500, 256, 0, stream>>>(wcat, zt, bias, qg, kg, vtg);
    attn_k<<<3200, 256, 0, stream>>>(qg, kg, vtg, attn, og);
    gemm_out_k<<<375, 256, 0, stream>>>(og, wout, out_b, outp);
}